// Round 9
// baseline (144.894 us; speedup 1.0000x reference)
//
#include <hip/hip_runtime.h>

// FreqLinear: out = Y2 @ float(idx)^T + corr[m] + bias[o], K = 2048.
// GEMM v9: m97-style lockstep double-buffer, 4 blocks/CU TLP.
// grid 1024 = 256 col-groups x 4 row-quarters; block 256 thr = 4 waves.
// Block = 32 cols x 64 rows (wave -> 1 mg = 16 rows, g = 0..1 col-halves).
// K-loop: 8 chunks of BK=256, LDS 2 x 16 KB ping-pong.
// Per-iter issue order (per wave):  COMPUTE(c) -> WRITE(c+1) -> ABURST(c+1)
//   -> LOADS(c+2) -> barrier.  In-order vmcnt consequence: compute's A-waits
//   only drain A (oldest); the lone exposed stall is WRITE draining its own
//   chunk's HBM loads -- covered by the 3 other resident blocks.
// LDS map: addr(col,pair) = col*512 + ((pair^col)*16), pair = 16B k-unit.
//   Writes: 8 lanes per 4-bank group (conflict-free). Reads (b128 frags):
//   8 lanes per 4-bank group (conflict-free). v8's 1040-B stride was 8-way
//   conflicted (1M SQ_LDS_BANK_CONFLICT) -- fixed here.
// Barrier = s_barrier + lgkmcnt(0) only (no vmcnt drain).

typedef __attribute__((ext_vector_type(8))) short bf16x8;   // 8 bf16
typedef __attribute__((ext_vector_type(4))) float f32x4;

#define K_TOT   2048
#define N_TOT   8192
#define NT      32        // cols per block
#define NCHUNK  8         // K chunks of 256
#define SPC     8         // ksteps (K=32) per chunk

__device__ __forceinline__ unsigned short f2bf_rn(float f) {
    unsigned u = __float_as_uint(f);
    u += 0x7FFFu + ((u >> 16) & 1u);
    return (unsigned short)(u >> 16);
}
// two ints (0..255) -> exact floats -> packed bf16 pair (truncation exact)
__device__ __forceinline__ unsigned pack2(int a, int b) {
    unsigned ua = __float_as_uint((float)a);
    unsigned ub = __float_as_uint((float)b);
    return __builtin_amdgcn_perm(ub, ua, 0x07060302u);
}

__device__ __forceinline__ void lds_barrier() {
    asm volatile("" ::: "memory");
    __builtin_amdgcn_s_waitcnt(0xC07F);   // lgkmcnt(0) only
    __builtin_amdgcn_s_barrier();
    asm volatile("" ::: "memory");
}

// ---------------- Kernel A: build Y2f (bf16, frag order) + corr ------------
__global__ __launch_bounds__(256) void prep_kernel(
    const float* __restrict__ x, const float* __restrict__ c_min,
    const float* __restrict__ c_range, unsigned short* __restrict__ Y2f,
    float* __restrict__ corr)
{
    __shared__ float Bk[8][16];
    __shared__ float scmin[8];
    __shared__ float ss[8];
    __shared__ float red[4];
    const int tid = threadIdx.x;
    const int m = blockIdx.x;
    if (tid < 128) {
        int k = tid >> 4, t = tid & 15;
        float v = cosf(3.14159265358979f * (t + 0.5f) * (float)k / 16.0f)
                  * 0.353553390593274f;                 // sqrt(2/16)
        if (k == 0) v *= 0.707106781186548f;            // 1/sqrt(2)
        Bk[k][t] = v;
    }
    if (tid < 8) {
        scmin[tid] = c_min[tid];
        ss[tid] = c_range[tid] * (1.0f / 255.0f);
    }
    __syncthreads();

    const float* xp = x + (long)m * 4096 + tid * 16;
    float xs[16];
#pragma unroll
    for (int q = 0; q < 4; ++q) {
        float4 v = *(const float4*)(xp + q * 4);
        xs[q * 4 + 0] = v.x; xs[q * 4 + 1] = v.y;
        xs[q * 4 + 2] = v.z; xs[q * 4 + 3] = v.w;
    }
    float partial = 0.0f;
    unsigned short yo[8];
#pragma unroll
    for (int k = 0; k < 8; ++k) {
        float y = 0.0f;
#pragma unroll
        for (int t = 0; t < 16; ++t) y += xs[t] * Bk[k][t];
        partial += y * scmin[k];
        yo[k] = f2bf_rn(y * ss[k]);
    }
    uint4 pk;
    pk.x = (unsigned)yo[0] | ((unsigned)yo[1] << 16);
    pk.y = (unsigned)yo[2] | ((unsigned)yo[3] << 16);
    pk.z = (unsigned)yo[4] | ((unsigned)yo[5] << 16);
    pk.w = (unsigned)yo[6] | ((unsigned)yo[7] << 16);
    // frag-order store: kc = tid>>2, fq = tid&3, mg = m>>4, fr = m&15
    {
        const int mg = m >> 4, fr = m & 15, kc = tid >> 2, fq = tid & 3;
        unsigned short* dst = Y2f + ((long)((mg * 64 + kc) * 64) + fq * 16 + fr) * 8;
        *(uint4*)dst = pk;
    }
#pragma unroll
    for (int off = 32; off > 0; off >>= 1)
        partial += __shfl_down(partial, off, 64);
    if ((tid & 63) == 0) red[tid >> 6] = partial;
    __syncthreads();
    if (tid == 0) corr[m] = red[0] + red[1] + red[2] + red[3];
}

// ---------------- Kernel B ------------------------------------------------
__global__ __launch_bounds__(256, 4) void gemm_kernel(
    const unsigned short* __restrict__ Y2f, const int* __restrict__ idx,
    const float* __restrict__ bias, const float* __restrict__ corr,
    float* __restrict__ out)
{
    __shared__ __align__(16) char lds[2][16384];

    const int tid  = threadIdx.x;
    const int wave = tid >> 6;
    const int lane = tid & 63;
    const int fr   = lane & 15;
    const int fq   = lane >> 4;
    const int cg   = blockIdx.x & 255;    // col group
    const int h    = blockIdx.x >> 8;     // row quarter 0..3
    const int o0   = cg * NT;
    const int mg   = h * 4 + wave;        // 0..15: rows [mg*16, mg*16+16)

    // staging map: thread -> col scol, pairs p = p0 + 8r (r=0..3, 32B each)
    const int scol = tid >> 3;            // 0..31
    const int p0   = tid & 7;
    const int* sBase = idx + (long)(o0 + scol) * K_TOT + p0 * 8;

    // A: frag(mg, ks) at bf16x8 index (mg*64 + ks)*64 + lane
    const bf16x8* aF = (const bf16x8*)Y2f + ((long)mg * 64) * 64 + lane;

    int4  S[2][8];     // reg-staged raw idx, 2 chunks
    bf16x8 a[2][8];    // A-frag double buffer (chunk-granular)
    f32x4 acc0 = {0.f,0.f,0.f,0.f}, acc1 = {0.f,0.f,0.f,0.f};

#define SLOAD(ch)                                                         \
    {                                                                     \
        _Pragma("unroll")                                                 \
        for (int r = 0; r < 4; ++r) {                                     \
            const int* p = sBase + (ch) * 256 + r * 64;                   \
            S[(ch) & 1][2 * r]     = *(const int4*)p;                     \
            S[(ch) & 1][2 * r + 1] = *(const int4*)(p + 4);               \
        }                                                                 \
    }

#define SWRITE(ch)                                                        \
    {                                                                     \
        char* buf = lds[(ch) & 1];                                        \
        _Pragma("unroll")                                                 \
        for (int r = 0; r < 4; ++r) {                                     \
            uint4 w;                                                      \
            w.x = pack2(S[(ch) & 1][2 * r].x,     S[(ch) & 1][2 * r].y);  \
            w.y = pack2(S[(ch) & 1][2 * r].z,     S[(ch) & 1][2 * r].w);  \
            w.z = pack2(S[(ch) & 1][2 * r + 1].x, S[(ch) & 1][2 * r + 1].y);\
            w.w = pack2(S[(ch) & 1][2 * r + 1].z, S[(ch) & 1][2 * r + 1].w);\
            *(uint4*)(buf + scol * 512 + (((p0 + 8 * r) ^ scol) * 16)) = w;\
        }                                                                 \
    }

#define ABURST(ch)                                                        \
    {                                                                     \
        _Pragma("unroll")                                                 \
        for (int s = 0; s < SPC; ++s)                                     \
            a[(ch) & 1][s] = aF[((ch) * SPC + s) * 64];                   \
    }

#define BREAD(ch, s, g)                                                   \
    (*(const bf16x8*)(lds[(ch) & 1] + (g * 16 + fr) * 512 +               \
                      ((((s) * 4 + fq) ^ (g * 16 + fr)) * 16)))

    // prologue
    SLOAD(0)
    SWRITE(0)
    SLOAD(1)
    ABURST(0)
    lds_barrier();

#pragma unroll
    for (int c = 0; c < NCHUNK; ++c) {
        // compute chunk c: A-waits hit only the oldest (a[c]) queue entries
#pragma unroll
        for (int s = 0; s < SPC; ++s) {
            bf16x8 b0 = BREAD(c, s, 0);
            bf16x8 b1 = BREAD(c, s, 1);
            acc0 = __builtin_amdgcn_mfma_f32_16x16x32_bf16(a[c & 1][s], b0, acc0, 0, 0, 0);
            acc1 = __builtin_amdgcn_mfma_f32_16x16x32_bf16(a[c & 1][s], b1, acc1, 0, 0, 0);
        }
        if (c + 1 < NCHUNK) SWRITE(c + 1)     // drains S(c+1) (1 iter old)
        if (c + 1 < NCHUNK) ABURST(c + 1)     // L2 A-prefetch, ages 1 iter
        if (c + 2 < NCHUNK) SLOAD(c + 2)      // HBM stream refill (newest)
        lds_barrier();
    }

    // epilogue: D layout col=lane&15, row=(lane>>4)*4+reg
    {
        const int col0 = o0 + fr;
        const float bv0 = bias[col0];
        const float bv1 = bias[col0 + 16];
        const int row0 = mg * 16 + fq * 4;
#pragma unroll
        for (int r = 0; r < 4; ++r) {
            const float cv = corr[row0 + r];
            const long ro = (long)(row0 + r) * N_TOT;
            out[ro + col0]      = acc0[r] + bv0 + cv;
            out[ro + col0 + 16] = acc1[r] + bv1 + cv;
        }
    }
#undef SLOAD
#undef SWRITE
#undef ABURST
#undef BREAD
}

extern "C" void kernel_launch(void* const* d_in, const int* in_sizes, int n_in,
                              void* d_out, int out_size, void* d_ws, size_t ws_size,
                              hipStream_t stream) {
    const float* x       = (const float*)d_in[0];   // [32,8,4096]
    const int*   idx     = (const int*)d_in[1];     // [2097152, 8]
    const float* c_min   = (const float*)d_in[2];   // [8]
    const float* c_range = (const float*)d_in[3];   // [8]
    const float* bias    = (const float*)d_in[4];   // [8192]
    float* out = (float*)d_out;                     // [256, 8192]

    unsigned short* Y2f = (unsigned short*)d_ws;                   // 1 MB
    float* corr = (float*)((char*)d_ws + (size_t)256 * K_TOT * 2); // 256 fp32

    prep_kernel<<<256, 256, 0, stream>>>(x, c_min, c_range, Y2f, corr);
    gemm_kernel<<<1024, 256, 0, stream>>>(Y2f, idx, bias, corr, out);
}